// Round 4
// baseline (2206.173 us; speedup 1.0000x reference)
//
#include <hip/hip_runtime.h>
#include <cstddef>

// Mix9Net directional-conv trunk, fully fused: one block = one (batch, direction)
// slice; all 12 layers computed with activations resident in LDS.
#define BATCH 256
#define HW 15
#define PADW 20                 // padded row stride (floats): 16B-aligned, <=2-way banks
#define CH 128
#define CHOUT 64
#define NRES 4
#define CHSTRIDE (HW*PADW)      // 300 floats per channel plane
#define NTH 512
#define LDS_FLOATS (CH*CHSTRIDE + 2*CHSTRIDE + PADW)  // h[128] + x[2] + zero row = 39020 (156,080 B)

// Thread map: lane = g*16 + r. g = output-channel group (4 ch), r = board row.
// r==15 is a "zero lane": it streams zeros so DPP row_shl:1 feeds row 14 a zero
// neighbor; it computes garbage and never stores.

__device__ __forceinline__ float silu_f(float v){ return v / (1.f + __expf(-v)); }

// DPP neighbor-row exchange within each 16-lane row (= one channel group).
// row_shr:1 -> lane r receives lane r-1 (row above); edge reads 0 (bound_ctrl).
// row_shl:1 -> lane r receives lane r+1 (row below); lane 15 supplies zeros.
__device__ __forceinline__ float dpp_shr1(float v){
  return __int_as_float(__builtin_amdgcn_update_dpp(0, __float_as_int(v), 0x111, 0xF, 0xF, true));
}
__device__ __forceinline__ float dpp_shl1(float v){
  return __int_as_float(__builtin_amdgcn_update_dpp(0, __float_as_int(v), 0x101, 0xF, 0xF, true));
}

__device__ __forceinline__ void load16(float r[16], const float* __restrict__ p){
  const float4* q = (const float4*)p;
  float4 a = q[0], b = q[1], c = q[2], d = q[3];
  r[0]=a.x; r[1]=a.y; r[2]=a.z;  r[3]=a.w;
  r[4]=b.x; r[5]=b.y; r[6]=b.z;  r[7]=b.w;
  r[8]=c.x; r[9]=c.y; r[10]=c.z; r[11]=c.w;
  r[12]=d.x; r[13]=d.y; r[14]=d.z; r[15]=d.w;
}

template<int U>
__device__ __forceinline__ float f4get(float4 v){
  return (U==0) ? v.x : (U==1) ? v.y : (U==2) ? v.z : v.w;
}

__device__ __forceinline__ void zero4(float a[4][HW]){
#pragma unroll
  for (int j=0;j<4;j++)
#pragma unroll
    for (int c=0;c<HW;c++) a[j][c]=0.f;
}

__device__ __forceinline__ void bias_silu4(float a[4][HW], const float* __restrict__ bp){
  float4 bv = *(const float4*)bp;
  float bb[4] = {bv.x, bv.y, bv.z, bv.w};
#pragma unroll
  for (int j=0;j<4;j++)
#pragma unroll
    for (int c=0;c<HW;c++) a[j][c] = silu_f(a[j][c] + bb[j]);
}

__device__ __forceinline__ void add4(float a[4][HW], const float r[4][HW]){
#pragma unroll
  for (int j=0;j<4;j++)
#pragma unroll
    for (int c=0;c<HW;c++) a[j][c] += r[j][c];
}

// Store/load own 4ch x 15col slice. Pad cols 15..19 must stay ZERO (edge taps
// read col 15), so write 3x float4 + 3 scalars, never the pad.
__device__ __forceinline__ void store4(float* __restrict__ hb, int o0, int r, const float a[4][HW]){
#pragma unroll
  for (int j=0;j<4;j++){
    float* p = hb + (o0+j)*CHSTRIDE + r*PADW;
    *(float4*)(p  ) = make_float4(a[j][0],a[j][1],a[j][2], a[j][3]);
    *(float4*)(p+4) = make_float4(a[j][4],a[j][5],a[j][6], a[j][7]);
    *(float4*)(p+8) = make_float4(a[j][8],a[j][9],a[j][10],a[j][11]);
    p[12]=a[j][12]; p[13]=a[j][13]; p[14]=a[j][14];
  }
}

__device__ __forceinline__ void snap4(float s[4][HW], const float* __restrict__ hb, int o0, int r){
#pragma unroll
  for (int j=0;j<4;j++){
    const float* p = hb + (o0+j)*CHSTRIDE + r*PADW;
    float4 a = *(const float4*)(p), b = *(const float4*)(p+4), c = *(const float4*)(p+8);
    s[j][0]=a.x; s[j][1]=a.y; s[j][2]=a.z;  s[j][3]=a.w;
    s[j][4]=b.x; s[j][5]=b.y; s[j][6]=b.z;  s[j][7]=b.w;
    s[j][8]=c.x; s[j][9]=c.y; s[j][10]=c.z; s[j][11]=c.w;
    s[j][12]=p[12]; s[j][13]=p[13]; s[j][14]=p[14];
  }
}

// 3-tap application. taps (dy,dx): D0:(0,-1)(0,0)(0,+1)  D1:(-1,0)(0,0)(+1,0)
// D2:(-1,-1)(0,0)(+1,+1)  D3:(+1,-1)(0,0)(-1,+1)   [matches _POS]
template<int DIR>
__device__ __forceinline__ void taps_fma(const float r0[16], const float rm[16],
    const float rp[16], const float w0a[4], const float w1a[4], const float w2a[4],
    float acc[4][HW])
{
#pragma unroll
  for (int c=0;c<HW;c++){
    float v1 = r0[c];
    float v0, v2;
    if      (DIR==0){ v0 = (c>0)?r0[c-1]:0.f; v2 = r0[c+1]; }
    else if (DIR==1){ v0 = rm[c];             v2 = rp[c];   }
    else if (DIR==2){ v0 = (c>0)?rm[c-1]:0.f; v2 = rp[c+1]; }
    else            { v0 = (c>0)?rp[c-1]:0.f; v2 = rm[c+1]; }
#pragma unroll
    for (int j=0;j<4;j++)
      acc[j][c] = fmaf(w2a[j], v2, fmaf(w1a[j], v1, fmaf(w0a[j], v0, acc[j][c])));
  }
}

// dconv0: 2 input channels, weights w3[k][o][i] = dconv0_w [3][128][2]
template<int DIR>
__device__ __forceinline__ void dconv_first(const float* __restrict__ xb,
    const float* __restrict__ wt, int o0, int r, const float* __restrict__ zr,
    float acc[4][HW])
{
  const float* p0 = (r < HW) ? (xb + r*PADW) : zr;
  const int st = (r < HW) ? CHSTRIDE : 0;
  float2 wq[3][4];
#pragma unroll
  for (int k=0;k<3;k++)
#pragma unroll
    for (int j=0;j<4;j++)
      wq[k][j] = *(const float2*)(wt + ((size_t)(k*CH + o0 + j))*2);
#pragma unroll
  for (int u=0;u<2;u++){
    float r0[16]; load16(r0, p0); p0 += st;
    float rm[16], rp[16];
    if (DIR != 0){
#pragma unroll
      for (int c=0;c<16;c++){ rm[c]=dpp_shr1(r0[c]); rp[c]=dpp_shl1(r0[c]); }
    }
    float w0a[4], w1a[4], w2a[4];
#pragma unroll
    for (int j=0;j<4;j++){
      w0a[j] = u ? wq[0][j].y : wq[0][j].x;
      w1a[j] = u ? wq[1][j].y : wq[1][j].x;
      w2a[j] = u ? wq[2][j].y : wq[2][j].x;
    }
    taps_fma<DIR>(r0, (DIR==0)?r0:rm, (DIR==0)?r0:rp, w0a, w1a, w2a, acc);
  }
}

// Residual-block dconv: 128 in-ch, weights [3][128][128] (k,o,i) — contiguous in i.
template<int DIR>
__device__ __forceinline__ void dconv_res(const float* __restrict__ hb,
    const float* __restrict__ wt, int o0, int r, const float* __restrict__ zr,
    float acc[4][HW])
{
  const float* p0 = (r < HW) ? (hb + r*PADW) : zr;
  const int st = (r < HW) ? CHSTRIDE : 0;
#pragma unroll 1
  for (int ic0=0; ic0<CH; ic0+=4){
    float4 wq[3][4];
#pragma unroll
    for (int k=0;k<3;k++)
#pragma unroll
      for (int j=0;j<4;j++)
        wq[k][j] = *(const float4*)(wt + ((size_t)(k*CH + o0 + j))*CH + ic0);
#pragma unroll
    for (int u=0;u<4;u++){
      float r0[16]; load16(r0, p0); p0 += st;
      float rm[16], rp[16];
      if (DIR != 0){
#pragma unroll
        for (int c=0;c<16;c++){ rm[c]=dpp_shr1(r0[c]); rp[c]=dpp_shl1(r0[c]); }
      }
      float w0a[4], w1a[4], w2a[4];
#pragma unroll
      for (int j=0;j<4;j++){
        if      (u==0){ w0a[j]=f4get<0>(wq[0][j]); w1a[j]=f4get<0>(wq[1][j]); w2a[j]=f4get<0>(wq[2][j]); }
        else if (u==1){ w0a[j]=f4get<1>(wq[0][j]); w1a[j]=f4get<1>(wq[1][j]); w2a[j]=f4get<1>(wq[2][j]); }
        else if (u==2){ w0a[j]=f4get<2>(wq[0][j]); w1a[j]=f4get<2>(wq[1][j]); w2a[j]=f4get<2>(wq[2][j]); }
        else          { w0a[j]=f4get<3>(wq[0][j]); w1a[j]=f4get<3>(wq[1][j]); w2a[j]=f4get<3>(wq[2][j]); }
      }
      taps_fma<DIR>(r0, (DIR==0)?r0:rm, (DIR==0)?r0:rp, w0a, w1a, w2a, acc);
    }
  }
}

// Pointwise conv accumulate; weights w[o][i] (row-major, contiguous in i).
template<int OT>
__device__ __forceinline__ void pw_accum(const float* __restrict__ hb,
    const float* __restrict__ wt, int o0, int r, const float* __restrict__ zr,
    float acc[OT][HW])
{
  const float* p0 = (r < HW) ? (hb + r*PADW) : zr;
  const int st = (r < HW) ? CHSTRIDE : 0;
#pragma unroll 1
  for (int ic0=0; ic0<CH; ic0+=4){
    float4 wq[OT];
#pragma unroll
    for (int j=0;j<OT;j++) wq[j] = *(const float4*)(wt + (size_t)(o0+j)*CH + ic0);
#pragma unroll
    for (int u=0;u<4;u++){
      float rr[16]; load16(rr, p0); p0 += st;
#pragma unroll
      for (int j=0;j<OT;j++){
        float w = (u==0)?f4get<0>(wq[j]):(u==1)?f4get<1>(wq[j]):(u==2)?f4get<2>(wq[j]):f4get<3>(wq[j]);
#pragma unroll
        for (int c=0;c<HW;c++) acc[j][c] = fmaf(w, rr[c], acc[j][c]);
      }
    }
  }
}

struct P {
  const float *w0, *b0, *wdc, *bdc, *wc1, *bc1, *w01, *b01, *w02, *b02, *wf, *bf;
};

template<int DIR>
__device__ __forceinline__ void run_dir(float* __restrict__ hb, const float* __restrict__ xb,
    const float* __restrict__ zr, int g, int r, int b, const P p, float* __restrict__ out)
{
  const int o0 = g*4;
  const bool act = (r < HW);
  float acc[4][HW];

  // layer 0: h = silu(dconv0(x))
  zero4(acc);
  dconv_first<DIR>(xb, p.w0, o0, r, zr, acc);
  bias_silu4(acc, p.b0 + o0);
  if (act) store4(hb, o0, r, acc);
  __syncthreads();

  // 4 directional res blocks
  for (int res=0; res<NRES; res++){
    const float* wd = p.wdc + (size_t)res*3*CH*CH;
    const float* wc = p.wc1 + (size_t)res*CH*CH;
    float rsd[4][HW];
    zero4(acc);
    dconv_res<DIR>(hb, wd, o0, r, zr, acc);      // reads all of h (own row + DPP)
    bias_silu4(acc, p.bdc + res*CH + o0);
    snap4(rsd, hb, o0, r);                        // own slice of old h (residual)
    __syncthreads();                              // all reads of h done
    if (act) store4(hb, o0, r, acc);              // h <- t
    __syncthreads();
    zero4(acc);
    pw_accum<4>(hb, wc, o0, r, zr, acc);          // reads all of t
    bias_silu4(acc, p.bc1 + res*CH + o0);
    add4(acc, rsd);
    __syncthreads();
    if (act) store4(hb, o0, r, acc);
    __syncthreads();
  }

  // Conv0dResBlock
  {
    float rsd[4][HW];
    zero4(acc);
    pw_accum<4>(hb, p.w01, o0, r, zr, acc);
    bias_silu4(acc, p.b01 + o0);
    snap4(rsd, hb, o0, r);
    __syncthreads();
    if (act) store4(hb, o0, r, acc);
    __syncthreads();
    zero4(acc);
    pw_accum<4>(hb, p.w02, o0, r, zr, acc);
    bias_silu4(acc, p.b02 + o0);
    add4(acc, rsd);
    __syncthreads();
    if (act) store4(hb, o0, r, acc);
    __syncthreads();
  }

  // final 1x1: 128 -> 64, no activation. Each group writes 2 output channels.
  {
    float a2[2][HW];
#pragma unroll
    for (int j=0;j<2;j++)
#pragma unroll
      for (int c=0;c<HW;c++) a2[j][c]=0.f;
    const int of0 = g*2;
    pw_accum<2>(hb, p.wf, of0, r, zr, a2);
    if (act){
      float* ob = out + ((size_t)(b*4 + DIR)*CHOUT + of0)*(HW*HW) + r*HW;
#pragma unroll
      for (int j=0;j<2;j++){
        float bb = p.bf[of0+j];
#pragma unroll
        for (int c=0;c<HW;c++) ob[(size_t)j*(HW*HW) + c] = a2[j][c] + bb;
      }
    }
  }
}

__global__ __launch_bounds__(NTH, 2)
void mix9_fused(const float* __restrict__ x, const P p, float* __restrict__ out)
{
  __shared__ float lds[LDS_FLOATS];
  float* hb = lds;                       // [128][15][PADW]
  float* xb = lds + CH*CHSTRIDE;         // [2][15][PADW]
  float* zr = xb + 2*CHSTRIDE;           // [PADW] zeros (fed to lane r==15)
  const int tid = threadIdx.x;
  const int bid = blockIdx.x;
  const int d = bid & 3;                 // direction fastest: x reuse in L2
  const int b = bid >> 2;

  for (int i = tid; i < LDS_FLOATS; i += NTH) lds[i] = 0.f;
  __syncthreads();

  const float* xs = x + (size_t)b*(2*HW*HW);
  for (int i = tid; i < 2*HW*HW; i += NTH){
    int ic = i/(HW*HW), rem = i%(HW*HW);
    xb[ic*CHSTRIDE + (rem/HW)*PADW + (rem%HW)] = xs[i];
  }
  __syncthreads();

  const int g = tid >> 4;   // 0..31: channel group
  const int r = tid & 15;   // 0..15: board row (15 = zero lane)

  switch (d){
    case 0:  run_dir<0>(hb, xb, zr, g, r, b, p, out); break;
    case 1:  run_dir<1>(hb, xb, zr, g, r, b, p, out); break;
    case 2:  run_dir<2>(hb, xb, zr, g, r, b, p, out); break;
    default: run_dir<3>(hb, xb, zr, g, r, b, p, out); break;
  }
}

extern "C" void kernel_launch(void* const* d_in, const int* in_sizes, int n_in,
                              void* d_out, int out_size, void* d_ws, size_t ws_size,
                              hipStream_t stream)
{
  (void)in_sizes; (void)n_in; (void)d_ws; (void)ws_size; (void)out_size;
  P p;
  p.w0  = (const float*)d_in[1];   // [3][128][2]
  p.b0  = (const float*)d_in[2];   // [128]
  p.wdc = (const float*)d_in[3];   // [4][3][128][128]
  p.bdc = (const float*)d_in[4];   // [4][128]
  p.wc1 = (const float*)d_in[5];   // [4][128][128]
  p.bc1 = (const float*)d_in[6];   // [4][128]
  p.w01 = (const float*)d_in[7];   // [128][128]
  p.b01 = (const float*)d_in[8];
  p.w02 = (const float*)d_in[9];
  p.b02 = (const float*)d_in[10];
  p.wf  = (const float*)d_in[11];  // [64][128]
  p.bf  = (const float*)d_in[12];  // [64]

  mix9_fused<<<dim3(BATCH*4), dim3(NTH), 0, stream>>>((const float*)d_in[0], p, (float*)d_out);
}

// Round 6
// 533.880 us; speedup vs baseline: 4.1323x; 4.1323x over previous
//
#include <hip/hip_runtime.h>
#include <cstdint>
#include <cstddef>

// Mix9Net trunk via MFMA: one block = one (batch, direction) slice.
// Activations: f16 in LDS, zero-padded 17x17 spatial grid, channel-contiguous,
// XOR-swizzled. Weights: staged per layer (per tap) into LDS as f16, swizzled.
// Every layer is C[128 out][225 pos] = W * h done with mfma_f32_16x16x32_f16,
// fp32 accum; bias/silu/residual in registers; in-place f16 writeback.

#define HWX 15
#define NPOS 225
#define CH 128
#define CHOUT 64
#define NTH 512
#define PADG 17
#define PPN (PADG*PADG)          // 289 padded positions
#define ROWB (CH*2)              // 256 B of channels per position
#define WOFF 0
#define WBYTES (CH*CH*2)         // 32 KB weight stage
#define HOFF WBYTES
#define LDS_BYTES (HOFF + PPN*ROWB)  // 32768 + 73984 = 106752 B
#define SAFE_PP (8*PADG+8)       // center cell: all tap shifts stay in-bounds

typedef _Float16 f16;
typedef __attribute__((ext_vector_type(8))) _Float16 f16x8;
typedef __attribute__((ext_vector_type(4))) _Float16 f16x4;
typedef __attribute__((ext_vector_type(4))) float f32x4;

// LDS addressing. Swizzle key (idx&15)<<4 keeps 16B alignment for b128 reads
// and reduces the pos-stride-256B 16-way conflict to 2-way (free per m136).
__device__ __forceinline__ int haddr(int pp, int ch){
  return HOFF + pp*ROWB + ((ch*2) ^ ((pp&15)<<4));
}
__device__ __forceinline__ int waddr(int o, int i){
  return WOFF + o*256 + ((i*2) ^ ((o&15)<<4));
}
__device__ __forceinline__ float silu_f(float v){ return v / (1.f + __expf(-v)); }

template<int MT>
__device__ __forceinline__ void zacc(f32x4* a){
#pragma unroll
  for (int m=0;m<MT;m++) a[m] = (f32x4){0.f,0.f,0.f,0.f};
}

// One GEMM pass over staged W and h (pp0t/pp1t may include a tap shift).
// A-frag: lane holds W[mt*16 + (lane&15)][krow*8 + j]  (j=0..7)
// B-frag: lane holds h[ch=krow*8+j][pos tile col lane&15]
// D:      col=lane&15 (pos), row=krow*4+reg (ch)   [guide §3, m89-verified]
template<int MT, int KB>
__device__ __forceinline__ void gemm(const char* sm, int pp0t, int pp1t,
                                     int krow, int col, f32x4* acc0, f32x4* acc1){
#pragma unroll
  for (int kb=0; kb<KB; kb++){
    const int ch0 = kb*32 + krow*8;
    f16x8 b0 = *(const f16x8*)(sm + haddr(pp0t, ch0));
    f16x8 b1 = *(const f16x8*)(sm + haddr(pp1t, ch0));
#pragma unroll
    for (int mt=0; mt<MT; mt++){
      f16x8 a = *(const f16x8*)(sm + waddr(mt*16+col, ch0));
      acc0[mt] = __builtin_amdgcn_mfma_f32_16x16x32_f16(a, b0, acc0[mt], 0, 0, 0);
      acc1[mt] = __builtin_amdgcn_mfma_f32_16x16x32_f16(a, b1, acc1[mt], 0, 0, 0);
    }
  }
}

// Stage a [rows][128] fp32 weight matrix from global into swizzled f16 LDS.
// 512 threads x 32 elems covers 128x128 exactly; rows=64 idles half.
__device__ __forceinline__ void stage_w(char* sm, const float* __restrict__ w,
                                        int rows, int tid){
  const int base = tid*32;
  if (base < rows*CH){
    const int o = base >> 7, i0 = base & 127;
    const float* src = w + o*CH + i0;
#pragma unroll
    for (int q=0;q<4;q++){
      float4 fa = *(const float4*)(src + q*8);
      float4 fb = *(const float4*)(src + q*8 + 4);
      f16x8 hv = { (f16)fa.x,(f16)fa.y,(f16)fa.z,(f16)fa.w,
                   (f16)fb.x,(f16)fb.y,(f16)fb.z,(f16)fb.w };
      *(f16x8*)(sm + waddr(o, i0 + q*8)) = hv;
    }
  }
}

// Snapshot this lane's owned (pos, ch) slots (residual), f16-exact.
template<int MT>
__device__ __forceinline__ void snap(const char* sm, f16x4* r, int pp, int krow){
#pragma unroll
  for (int mt=0;mt<MT;mt++)
    r[mt] = *(const f16x4*)(sm + haddr(pp, mt*16 + krow*4));
}

// Writeback one N-tile: bias (+silu) (+residual), cvt to f16, store in place.
template<int MT, bool SILU, bool RES>
__device__ __forceinline__ void wb(char* sm, const f32x4* acc,
                                   const float* __restrict__ bias,
                                   const f16x4* rsd, int pp, bool valid, int krow){
#pragma unroll
  for (int mt=0;mt<MT;mt++){
    const int ch0 = mt*16 + krow*4;
    float4 bb = *(const float4*)(bias + ch0);
    f32x4 v = acc[mt];
    v[0]+=bb.x; v[1]+=bb.y; v[2]+=bb.z; v[3]+=bb.w;
    if (SILU){
#pragma unroll
      for (int j=0;j<4;j++) v[j] = silu_f(v[j]);
    }
    if (RES){
      f16x4 r = rsd[mt];
#pragma unroll
      for (int j=0;j<4;j++) v[j] += (float)r[j];
    }
    if (valid){
      f16x4 o = { (f16)v[0],(f16)v[1],(f16)v[2],(f16)v[3] };
      *(f16x4*)(sm + haddr(pp, ch0)) = o;
    }
  }
}

struct P {
  const float *x, *w0, *b0, *wdc, *bdc, *wc1, *bc1, *w01, *b01, *w02, *b02, *wf, *bf;
};

__global__ __launch_bounds__(NTH, 1)
void mix9_mfma(const P p, float* __restrict__ out)
{
  __shared__ char sm[LDS_BYTES];
  const int tid  = threadIdx.x;
  const int lane = tid & 63;
  const int wave = tid >> 6;
  const int col  = lane & 15;
  const int krow = lane >> 4;
  const int d = blockIdx.x & 3;
  const int b = blockIdx.x >> 2;

  // zero h grid (borders must stay 0 forever) and W buffer (layer-0 K-padding)
  for (int i = tid*16; i < PPN*ROWB; i += NTH*16)
    *(f32x4*)(sm + HOFF + i) = (f32x4){0.f,0.f,0.f,0.f};
  for (int i = tid*16; i < WBYTES; i += NTH*16)
    *(f32x4*)(sm + i) = (f32x4){0.f,0.f,0.f,0.f};
  __syncthreads();

  // stage x (2 channels) into padded grid as f16
  for (int i = tid; i < 2*NPOS; i += NTH){
    const int ic = i / NPOS, n = i % NPOS;
    const int pp = (n/HWX + 1)*PADG + (n%HWX + 1);
    *(f16*)(sm + haddr(pp, ic)) = (f16)p.x[(size_t)b*2*NPOS + i];
  }

  // per-thread position constants (fixed for all layers)
  const int nt0 = wave*2, nt1 = wave*2 + 1;
  const int n0 = nt0*16 + col, n1 = nt1*16 + col;
  const bool v0 = n0 < NPOS, v1 = n1 < NPOS;
  const int pp0 = v0 ? (n0/HWX + 1)*PADG + (n0%HWX + 1) : SAFE_PP;
  const int pp1 = v1 ? (n1/HWX + 1)*PADG + (n1%HWX + 1) : SAFE_PP;

  // direction tap offsets: taps = {dneg, 0, -dneg} on the padded grid
  int dneg;
  switch (d){
    case 0:  dneg = -1;        break;   // horiz: (0,-1)
    case 1:  dneg = -PADG;     break;   // vert:  (-1,0)
    case 2:  dneg = -PADG - 1; break;   // diag:  (-1,-1)
    default: dneg =  PADG - 1; break;   // anti:  (+1,-1)
  }
  const int tap[3] = { dneg, 0, -dneg };

  f32x4 acc0[8], acc1[8];
  f16x4 rsd0[8], rsd1[8];
  __syncthreads();

  // ---- layer 0: h = silu(dconv0(x)), K-block 0 only (i<2 valid, rest zero) ----
  zacc<8>(acc0); zacc<8>(acc1);
#pragma unroll 1
  for (int k=0;k<3;k++){
    if (tid < 256)   // fill W[o][0..1] for tap k (other entries stay 0)
      *(f16*)(sm + waddr(tid>>1, tid&1)) = (f16)p.w0[k*256 + tid];
    __syncthreads();
    gemm<8,1>(sm, pp0+tap[k], pp1+tap[k], krow, col, acc0, acc1);
    __syncthreads();
  }
  wb<8,true,false>(sm, acc0, p.b0, nullptr, pp0, v0, krow);
  wb<8,true,false>(sm, acc1, p.b0, nullptr, pp1, v1, krow);

  // ---- 4 directional res blocks ----
#pragma unroll 1
  for (int res=0; res<4; res++){
    const float* wd = p.wdc + (size_t)res*3*CH*CH;
    zacc<8>(acc0); zacc<8>(acc1);
#pragma unroll 1
    for (int k=0;k<3;k++){
      stage_w(sm, wd + (size_t)k*CH*CH, CH, tid);
      __syncthreads();
      gemm<8,4>(sm, pp0+tap[k], pp1+tap[k], krow, col, acc0, acc1);
      __syncthreads();
    }
    snap<8>(sm, rsd0, pp0, krow);                 // residual = h (pre-dconv)
    snap<8>(sm, rsd1, pp1, krow);
    wb<8,true,false>(sm, acc0, p.bdc + res*CH, nullptr, pp0, v0, krow);
    wb<8,true,false>(sm, acc1, p.bdc + res*CH, nullptr, pp1, v1, krow);

    stage_w(sm, p.wc1 + (size_t)res*CH*CH, CH, tid);
    __syncthreads();
    zacc<8>(acc0); zacc<8>(acc1);
    gemm<8,4>(sm, pp0, pp1, krow, col, acc0, acc1);
    __syncthreads();
    wb<8,true,true>(sm, acc0, p.bc1 + res*CH, rsd0, pp0, v0, krow);
    wb<8,true,true>(sm, acc1, p.bc1 + res*CH, rsd1, pp1, v1, krow);
  }

  // ---- Conv0dResBlock ----
  stage_w(sm, p.w01, CH, tid);
  __syncthreads();
  zacc<8>(acc0); zacc<8>(acc1);
  gemm<8,4>(sm, pp0, pp1, krow, col, acc0, acc1);
  __syncthreads();
  snap<8>(sm, rsd0, pp0, krow);
  snap<8>(sm, rsd1, pp1, krow);
  wb<8,true,false>(sm, acc0, p.b01, nullptr, pp0, v0, krow);
  wb<8,true,false>(sm, acc1, p.b01, nullptr, pp1, v1, krow);

  stage_w(sm, p.w02, CH, tid);
  __syncthreads();
  zacc<8>(acc0); zacc<8>(acc1);
  gemm<8,4>(sm, pp0, pp1, krow, col, acc0, acc1);
  __syncthreads();
  wb<8,true,true>(sm, acc0, p.b02, rsd0, pp0, v0, krow);
  wb<8,true,true>(sm, acc1, p.b02, rsd1, pp1, v1, krow);

  // ---- final 1x1: 128 -> 64, +bias, no silu, store to global fp32 ----
  stage_w(sm, p.wf, CHOUT, tid);
  __syncthreads();
  zacc<4>(acc0); zacc<4>(acc1);
  gemm<4,4>(sm, pp0, pp1, krow, col, acc0, acc1);

  float* ob = out + ((size_t)(b*4 + d)*CHOUT)*NPOS;
#pragma unroll
  for (int mt=0;mt<4;mt++){
    const int ch0 = mt*16 + krow*4;
    float4 bb = *(const float4*)(p.bf + ch0);
    const float bj[4] = {bb.x, bb.y, bb.z, bb.w};
#pragma unroll
    for (int j=0;j<4;j++){
      if (v0) ob[(size_t)(ch0+j)*NPOS + n0] = acc0[mt][j] + bj[j];
      if (v1) ob[(size_t)(ch0+j)*NPOS + n1] = acc1[mt][j] + bj[j];
    }
  }
}

extern "C" void kernel_launch(void* const* d_in, const int* in_sizes, int n_in,
                              void* d_out, int out_size, void* d_ws, size_t ws_size,
                              hipStream_t stream)
{
  (void)in_sizes; (void)n_in; (void)d_ws; (void)ws_size; (void)out_size;
  P p;
  p.x   = (const float*)d_in[0];
  p.w0  = (const float*)d_in[1];   // [3][128][2]
  p.b0  = (const float*)d_in[2];   // [128]
  p.wdc = (const float*)d_in[3];   // [4][3][128][128]
  p.bdc = (const float*)d_in[4];   // [4][128]
  p.wc1 = (const float*)d_in[5];   // [4][128][128]
  p.bc1 = (const float*)d_in[6];   // [4][128]
  p.w01 = (const float*)d_in[7];   // [128][128]
  p.b01 = (const float*)d_in[8];
  p.w02 = (const float*)d_in[9];
  p.b02 = (const float*)d_in[10];
  p.wf  = (const float*)d_in[11];  // [64][128]
  p.bf  = (const float*)d_in[12];  // [64]

  mix9_mfma<<<dim3(256*4), dim3(NTH), 0, stream>>>(p, (float*)d_out);
}